// Round 7
// baseline (360.044 us; speedup 1.0000x reference)
//
#include <hip/hip_runtime.h>
#include <hip/hip_bf16.h>

// GCN encoder: 3 layers on N=100000 nodes, E=1250000 edges, 64 features.
// gcn(x) = relu(D^-1/2 (A+I) D^-1/2 (xW) + b)
// hs = dinv.*(xW) [gemm, bf16]; agg epilogue = bf16(relu(dinv*(hs_d+sum hs_s)+b))
// so each GEMM is a plain post-scaled product on a bf16/fp32 input.
// R1: dst-CSR gather (no fp32 atomics).  R2: hierarchical scan.
// R3: bucketed 2-phase CSR build.  R4: bf16 hs, slab build, b128 k-loop.
// R5: MLP-heavy aggregate.  R6 post-mortem: aggregate is L2-fill-rate bound
//     (FETCH 70MB @ ~1.25TB/s regardless of issue pattern) -> revert loop to
//     R5 form; attack the OTHER 246us: fuse inter-layer transform into
//     aggregate epilogue (bf16 out), fold bsum_scan into csr_local, memset
//     cursors, wave-shfl scans (2 barriers vs 20).

#define WG 256
#define BSHIFT 9                 // 512 nodes per bucket
#define BSIZE  (1 << BSHIFT)
#define BCAP   8192              // slots per bucket (mean 6400, ~22 sigma margin)
#define PCHUNK 2048              // edges per partition block
#define XS_LD  68                // xs leading dim: 16B-aligned, b128 reads

// Partition edges by dst-bucket into packed pairs ((dst&511)<<32 | src) in
// fixed per-bucket slabs. cur2 holds pure counts (memset 0 before).
// LDS histogram -> 1 global atomic per touched bucket -> stage in LDS in
// bucket-slot order -> linear write (coalesced runs per bucket).
__global__ __launch_bounds__(WG) void partition(const int* __restrict__ ei,
                                                int* __restrict__ cur2,
                                                unsigned long long* __restrict__ pairs,
                                                int E) {
    __shared__ int hist[256];
    __shared__ int gbase[256];
    __shared__ int lb[256];
    __shared__ int wtot[4], wpre[4];
    __shared__ unsigned long long sp[PCHUNK];
    __shared__ int sd[PCHUNK];
    const int t = threadIdx.x;
    const int lane = t & 63, w = t >> 6;
    const int base = blockIdx.x * PCHUNK;
    const int total = min(PCHUNK, E - base);

    hist[t] = 0;
    __syncthreads();

    int s[8], d[8], r[8];
#pragma unroll
    for (int i = 0; i < 8; i++) {
        int e = base + i * WG + t;           // coalesced
        bool ok = e < E;
        s[i] = ok ? ei[e] : 0;
        d[i] = ok ? ei[E + e] : 0;
        r[i] = ok ? atomicAdd(&hist[d[i] >> BSHIFT], 1) : 0;
        if (!ok) d[i] = -1;
    }
    __syncthreads();

    int hv = hist[t];
    int old = (hv > 0) ? atomicAdd(&cur2[t], hv) : 0;
    gbase[t] = t * BCAP + old;

    // exclusive scan of hist -> lb, via wave shfl (2 barriers total)
    int incl = hv;
#pragma unroll
    for (int ofs = 1; ofs < 64; ofs <<= 1) {
        int u = __shfl_up(incl, ofs);
        if (lane >= ofs) incl += u;
    }
    if (lane == 63) wtot[w] = incl;
    __syncthreads();
    if (t == 0) {
        int run = 0;
#pragma unroll
        for (int j = 0; j < 4; j++) { wpre[j] = run; run += wtot[j]; }
    }
    __syncthreads();
    lb[t] = wpre[w] + incl - hv;
    __syncthreads();

#pragma unroll
    for (int i = 0; i < 8; i++) {
        if (d[i] >= 0) {
            int b = d[i] >> BSHIFT;
            int slot = lb[b] + r[i];
            sp[slot] = ((unsigned long long)(unsigned)(d[i] & (BSIZE - 1)) << 32) |
                       (unsigned)s[i];
            sd[slot] = gbase[b] + r[i];
        }
    }
    __syncthreads();

    for (int j = t; j < total; j += WG)
        pairs[sd[j]] = sp[j];
}

// Per-bucket: own global prefix (serial 196-add by t0), LDS histogram over 512
// local nodes, wave-shfl scan, write off/dinv, fill private csr window.
__global__ __launch_bounds__(1024) void csr_local(const unsigned long long* __restrict__ pairs,
                                                  const int* __restrict__ cur2,
                                                  int* __restrict__ off,
                                                  float* __restrict__ dinv,
                                                  int* __restrict__ csr,
                                                  int N, int nbk, int E) {
    __shared__ int h[BSIZE];
    __shared__ int cur[BSIZE];
    __shared__ int wtot[8], wpre[8];
    __shared__ int base_s;
    const int b = blockIdx.x;
    const int t = threadIdx.x;
    const int node0 = b << BSHIFT;
    const int nlocal = min(BSIZE, N - node0);
    const int pstart = b * BCAP;
    const int pend = pstart + cur2[b];

    if (t < BSIZE) h[t] = 0;
    if (t == 0) {
        int run = 0;
        for (int j = 0; j < b; j++) run += cur2[j];   // ~196 LDS-free adds, cheap
        base_s = run;
        if (b == 0) off[N] = E;
    }
    __syncthreads();

    for (int e = pstart + t; e < pend; e += 1024)
        atomicAdd(&h[(int)(pairs[e] >> 32)], 1);
    __syncthreads();

    // scan h[0..511] with 8 waves (t<512), shfl within wave
    int deg = 0, incl = 0;
    const int lane = t & 63, w = t >> 6;
    if (t < BSIZE) {
        deg = h[t];
        incl = deg;
#pragma unroll
        for (int ofs = 1; ofs < 64; ofs <<= 1) {
            int u = __shfl_up(incl, ofs);
            if (lane >= ofs) incl += u;
        }
        if (lane == 63) wtot[w] = incl;
    }
    __syncthreads();
    if (t == 0) {
        int run = 0;
#pragma unroll
        for (int j = 0; j < 8; j++) { wpre[j] = run; run += wtot[j]; }
    }
    __syncthreads();
    if (t < nlocal) {
        int pos = base_s + wpre[w] + incl - deg;   // exclusive prefix
        off[node0 + t] = pos;
        cur[t] = pos;
        dinv[node0 + t] = rsqrtf((float)(deg + 1));
    }
    __syncthreads();

    for (int e = pstart + t; e < pend; e += 1024) {
        unsigned long long p = pairs[e];
        int local = (int)(p >> 32);
        int src = (int)(p & 0xffffffffu);
        int pos = atomicAdd(&cur[local], 1);
        csr[pos] = src;
    }
}

// GEMM: out = post(in @ W); post = (post_scale ? dinv[row]* : ) + (b_post?:0)
// in: fp32 or bf16 (in_bf16); out: bf16 (hs buffer) or fp32 (d_out).
__global__ __launch_bounds__(WG) void gemm_fused(
    const void* __restrict__ in, int in_bf16, const float* __restrict__ W,
    const float* __restrict__ dinv, int post_scale, const float* __restrict__ b_post,
    void* __restrict__ out1, int out_bf16, int n_rows)
{
    __shared__ float Ws[64 * 64];
    __shared__ float xs[64 * XS_LD];

    const int t = threadIdx.x;
    const int row0 = blockIdx.x * 64;

    const float4* W4 = (const float4*)W;
    float4* Ws4 = (float4*)Ws;
#pragma unroll
    for (int i = 0; i < 4; i++) Ws4[i * WG + t] = W4[i * WG + t];

#pragma unroll
    for (int i = 0; i < 4; i++) {
        int j = i * WG + t;
        int rr = j >> 4;
        int c  = (j & 15) * 4;
        int row = row0 + rr;
        float4 v = make_float4(0.f, 0.f, 0.f, 0.f);
        if (row < n_rows) {
            if (in_bf16) {
                ushort4 u = *(const ushort4*)((const unsigned short*)in +
                                              ((size_t)row << 6) + c);
                union { unsigned q; float f; } a0, a1, a2, a3;
                a0.q = (unsigned)u.x << 16; a1.q = (unsigned)u.y << 16;
                a2.q = (unsigned)u.z << 16; a3.q = (unsigned)u.w << 16;
                v = make_float4(a0.f, a1.f, a2.f, a3.f);
            } else {
                v = *(const float4*)((const float*)in + ((size_t)row << 6) + c);
            }
        }
        float* xp = xs + rr * XS_LD + c;
        xp[0] = v.x; xp[1] = v.y; xp[2] = v.z; xp[3] = v.w;
    }
    __syncthreads();

    const int fg = (t & 15) * 4;
    const int r0 = (t >> 4) * 4;
    float acc[4][4] = {};

#pragma unroll
    for (int kq = 0; kq < 64; kq += 4) {          // k-quads: b128 xs reads
        float4 xr[4];
#pragma unroll
        for (int r = 0; r < 4; r++)
            xr[r] = *(const float4*)(xs + (r0 + r) * XS_LD + kq);
#pragma unroll
        for (int kk = 0; kk < 4; kk++) {
            float4 wv = *(const float4*)(Ws + (kq + kk) * 64 + fg);
#pragma unroll
            for (int r = 0; r < 4; r++) {
                float xv = ((const float*)&xr[r])[kk];
                acc[r][0] = fmaf(xv, wv.x, acc[r][0]);
                acc[r][1] = fmaf(xv, wv.y, acc[r][1]);
                acc[r][2] = fmaf(xv, wv.z, acc[r][2]);
                acc[r][3] = fmaf(xv, wv.w, acc[r][3]);
            }
        }
    }

    float4 bp = b_post ? *(const float4*)(b_post + fg) : make_float4(0.f, 0.f, 0.f, 0.f);
#pragma unroll
    for (int r = 0; r < 4; r++) {
        int row = row0 + r0 + r;
        if (row >= n_rows) break;
        float sc = post_scale ? dinv[row] : 1.0f;
        float4 o;
        o.x = fmaf(acc[r][0], sc, bp.x);
        o.y = fmaf(acc[r][1], sc, bp.y);
        o.z = fmaf(acc[r][2], sc, bp.z);
        o.w = fmaf(acc[r][3], sc, bp.w);
        if (out_bf16) {
            union { __hip_bfloat16 h[4]; ushort4 u; } pk;
            pk.h[0] = __float2bfloat16(o.x);
            pk.h[1] = __float2bfloat16(o.y);
            pk.h[2] = __float2bfloat16(o.z);
            pk.h[3] = __float2bfloat16(o.w);
            *(ushort4*)((unsigned short*)out1 + ((size_t)row << 6) + fg) = pk.u;
        } else {
            *(float4*)((float*)out1 + ((size_t)row << 6) + fg) = o;
        }
    }
}

// Segmented gather-reduce + fused next-layer input transform:
// O[d] = bf16( relu( dinv[d]*(A[d] + sum A[csr[e]]) + bias ) )
// One wave per node, lane = feature (bf16 loads, fp32 accumulate).
__global__ __launch_bounds__(WG) void aggregate(
    const __hip_bfloat16* __restrict__ A, __hip_bfloat16* __restrict__ O,
    const int* __restrict__ off, const int* __restrict__ csr,
    const float* __restrict__ dinv, const float* __restrict__ bias, int N)
{
    int node = blockIdx.x * 4 + (threadIdx.x >> 6);
    if (node >= N) return;
    int lane = threadIdx.x & 63;

    int s0 = off[node];
    int s1 = off[node + 1];
    float acc = __bfloat162float(A[((size_t)node << 6) + lane]);   // self-loop

    int e = s0;
    for (; e + 4 <= s1; e += 4) {              // 4-edge ILP
        int i0 = csr[e], i1 = csr[e + 1], i2 = csr[e + 2], i3 = csr[e + 3];
        float v0 = __bfloat162float(A[((size_t)i0 << 6) + lane]);
        float v1 = __bfloat162float(A[((size_t)i1 << 6) + lane]);
        float v2 = __bfloat162float(A[((size_t)i2 << 6) + lane]);
        float v3 = __bfloat162float(A[((size_t)i3 << 6) + lane]);
        acc += (v0 + v1) + (v2 + v3);
    }
    for (; e < s1; e++)
        acc += __bfloat162float(A[((size_t)csr[e] << 6) + lane]);

    float v = fmaxf(fmaf(dinv[node], acc, bias[lane]), 0.f);
    O[((size_t)node << 6) + lane] = __float2bfloat16(v);
}

extern "C" void kernel_launch(void* const* d_in, const int* in_sizes, int n_in,
                              void* d_out, int out_size, void* d_ws, size_t ws_size,
                              hipStream_t stream) {
    const float* x  = (const float*)d_in[0];
    const int*   ei = (const int*)d_in[1];
    const float* W1 = (const float*)d_in[2];
    const float* b1 = (const float*)d_in[3];
    const float* W2 = (const float*)d_in[4];
    const float* b2 = (const float*)d_in[5];
    const float* W3 = (const float*)d_in[6];
    const float* b3 = (const float*)d_in[7];
    float* out = (float*)d_out;

    const int N = in_sizes[0] / 64;    // 100000
    const int E = in_sizes[1] / 2;     // 1250000
    const int nbk = (N + BSIZE - 1) / BSIZE;        // 196 buckets

    // workspace layout
    int*   off  = (int*)d_ws;                       // N+1
    int*   csr  = off + (N + 1);                    // E
    int*   cur2 = csr + E;                          // 256 (bucket counts)
    uintptr_t pa = (uintptr_t)(cur2 + 256);
    pa = (pa + 255) & ~(uintptr_t)255;
    float* dinv = (float*)pa;                       // N
    uintptr_t sa = (uintptr_t)(dinv + N);
    sa = (sa + 255) & ~(uintptr_t)255;
    // slab0: pairs (nbk*BCAP*8 = 12.85MB) then reused as A (12.8MB bf16):
    // pairs dead after csr_local, A born at gemm1 (stream-ordered).
    unsigned long long* pairs = (unsigned long long*)sa;
    __hip_bfloat16* A = (__hip_bfloat16*)sa;
    size_t slab0 = (size_t)nbk * BCAP * 8;          // >= N*64*2
    __hip_bfloat16* H = (__hip_bfloat16*)(sa + ((slab0 + 255) & ~(size_t)255));

    const int gG = (N + 63) / 64;
    const int gA = (N + 3) / 4;
    const int gP = (E + PCHUNK - 1) / PCHUNK;

    // CSR build (per call; ws re-poisoned every launch)
    hipMemsetAsync(cur2, 0, 256 * sizeof(int), stream);
    partition<<<gP,  WG,   0, stream>>>(ei, cur2, pairs, E);
    csr_local<<<nbk, 1024, 0, stream>>>(pairs, cur2, off, dinv, csr, N, nbk, E);

    // Layer 1: A = bf16(dinv.*(x@W1)); H = bf16(relu(dinv*(A_d+sum A_s)+b1))
    gemm_fused<<<gG, WG, 0, stream>>>(x, 0, W1, dinv, 1, nullptr, A, 1, N);
    aggregate <<<gA, WG, 0, stream>>>(A, H, off, csr, dinv, b1, N);

    // Layer 2: A = bf16(dinv.*(H@W2)); H = bf16(relu(dinv*(A_d+sum A_s)+b2))
    gemm_fused<<<gG, WG, 0, stream>>>(H, 1, W2, dinv, 1, nullptr, A, 1, N);
    aggregate <<<gA, WG, 0, stream>>>(A, H, off, csr, dinv, b2, N);

    // Layer 3: out = H@W3 + b3 (fp32)
    gemm_fused<<<gG, WG, 0, stream>>>(H, 1, W3, dinv, 0, b3, out, 0, N);
}